// Round 1
// baseline (251.195 us; speedup 1.0000x reference)
//
#include <hip/hip_runtime.h>

// GINConv fused: out[r] = (sum_{j<16} X[col[16r+j]]) @ W
// N=100000 nodes, DEG=16, D=128. Gather-BW bound (819 MB L3-resident gathers);
// GEMM via bf16 MFMA is ~free (3.28 GFLOP).

#define NNODES 100000
#define DEG 16
#define D 128
#define MT 32          // nodes per block
#define XPS 136        // sXp row stride in bf16 elems (=272B: 2-way bank alias, free)

typedef __attribute__((ext_vector_type(8))) short bf16x8;   // 8 bf16 = 4 VGPRs
typedef __attribute__((ext_vector_type(4))) float f32x4;

__device__ __forceinline__ unsigned short f2bf(float x) {
  // round-to-nearest-even fp32 -> bf16
  union { float f; unsigned u; } v; v.f = x;
  unsigned r = v.u + 0x7FFFu + ((v.u >> 16) & 1u);
  return (unsigned short)(r >> 16);
}

// W[k][n] (row-major 128x128 fp32) -> Wt[n][k] bf16 (B-fragment friendly:
// 8 consecutive k contiguous). Rerun every launch (d_ws is re-poisoned).
__global__ __launch_bounds__(256) void prep_wt(const float* __restrict__ W,
                                               unsigned short* __restrict__ Wt) {
  int t = blockIdx.x * 256 + threadIdx.x;   // 0..16383
  int n = t >> 7, k = t & 127;
  Wt[n * D + k] = f2bf(W[k * D + n]);       // writes coalesced; W L2-hot
}

__global__ __launch_bounds__(256) void gin_fused(
    const float* __restrict__ X, const int* __restrict__ colidx,
    const unsigned short* __restrict__ Wt, float* __restrict__ out) {
  __shared__ __align__(16) unsigned short sXp[MT * XPS];  // 8704 B bf16 X' tile
  __shared__ int sIdx[MT * DEG];                          // 2048 B indices

  const int tid  = threadIdx.x;
  const int wave = tid >> 6;
  const int lane = tid & 63;
  const long base_node = (long)blockIdx.x * MT;

  // stage this block's 512 column indices (256 threads x int2, coalesced)
  ((int2*)sIdx)[tid] = ((const int2*)(colidx + base_node * DEG))[tid];
  __syncthreads();

  // ---- aggregation: each wave owns 8 nodes; half-wave (32 lanes) per node ----
  const int half = lane >> 5;
  const int l32  = lane & 31;
  const float4* X4 = (const float4*)X;
  #pragma unroll
  for (int p = 0; p < 4; ++p) {
    int local = wave * 8 + p * 2 + half;
    float4 acc = make_float4(0.f, 0.f, 0.f, 0.f);
    #pragma unroll
    for (int j = 0; j < DEG; ++j) {           // 16 independent 16B gathers in flight
      int c = sIdx[local * DEG + j];
      float4 v = X4[(long)c * (D / 4) + l32]; // 32 lanes x 16B = 512B/row, coalesced
      acc.x += v.x; acc.y += v.y; acc.z += v.z; acc.w += v.w;
    }
    ushort4 b;
    b.x = f2bf(acc.x); b.y = f2bf(acc.y); b.z = f2bf(acc.z); b.w = f2bf(acc.w);
    *(ushort4*)(&sXp[local * XPS + l32 * 4]) = b;  // 8B store, contiguous per half-wave
  }
  __syncthreads();

  // ---- MFMA 16x16x32 bf16: wave w -> n-tiles {2w,2w+1} x m-tiles {0,1} ----
  // A-frag: A[m=lane&15][k=(lane>>4)*8+j]; B-frag: B[k=(lane>>4)*8+j][n=lane&15]
  const int fr   = lane & 15;
  const int quad = lane >> 4;
  f32x4 acc[2][2] = {{{0.f,0.f,0.f,0.f},{0.f,0.f,0.f,0.f}},
                     {{0.f,0.f,0.f,0.f},{0.f,0.f,0.f,0.f}}};
  #pragma unroll
  for (int ks = 0; ks < 4; ++ks) {
    int k0 = ks * 32 + quad * 8;
    bf16x8 a0 = *(const bf16x8*)(&sXp[fr        * XPS + k0]);  // ds_read_b128
    bf16x8 a1 = *(const bf16x8*)(&sXp[(16 + fr) * XPS + k0]);
    #pragma unroll
    for (int nt = 0; nt < 2; ++nt) {
      int n = (wave * 2 + nt) * 16 + fr;
      bf16x8 bfrag = *(const bf16x8*)(&Wt[n * D + k0]);        // 16B global, L2-hot
      acc[0][nt] = __builtin_amdgcn_mfma_f32_16x16x32_bf16(a0, bfrag, acc[0][nt], 0, 0, 0);
      acc[1][nt] = __builtin_amdgcn_mfma_f32_16x16x32_bf16(a1, bfrag, acc[1][nt], 0, 0, 0);
    }
  }

  // ---- epilogue: C/D layout col=lane&15, row=(lane>>4)*4+reg ----
  #pragma unroll
  for (int mt = 0; mt < 2; ++mt) {
    #pragma unroll
    for (int nt = 0; nt < 2; ++nt) {
      int col = (wave * 2 + nt) * 16 + fr;
      long rowbase = base_node + mt * 16 + quad * 4;
      #pragma unroll
      for (int r = 0; r < 4; ++r) {
        out[(rowbase + r) * D + col] = acc[mt][nt][r];  // 64B per quarter-wave
      }
    }
  }
}

extern "C" void kernel_launch(void* const* d_in, const int* in_sizes, int n_in,
                              void* d_out, int out_size, void* d_ws, size_t ws_size,
                              hipStream_t stream) {
  const float* X      = (const float*)d_in[0];   // [100000,128] fp32
  const float* W      = (const float*)d_in[1];   // [128,128] fp32
  const int*   colidx = (const int*)d_in[3];     // [1600000] int32
  float* out = (float*)d_out;                    // [100000,128] fp32
  unsigned short* Wt = (unsigned short*)d_ws;    // 32KB bf16 W^T

  hipLaunchKernelGGL(prep_wt, dim3(64), dim3(256), 0, stream, W, Wt);
  hipLaunchKernelGGL(gin_fused, dim3(NNODES / MT), dim3(256), 0, stream,
                     X, colidx, Wt, out);
}

// Round 2
// 211.948 us; speedup vs baseline: 1.1852x; 1.1852x over previous
//
#include <hip/hip_runtime.h>

// GINConv fused: out[r] = (sum_{j<16} X[col[16r+j]]) @ W
// N=100000, DEG=16, D=128. Gather-BW bound. R2: gather bf16 X (pre-converted
// into d_ws) -> halves the 819MB gather stream and improves L2 residency.

#define NNODES 100000
#define DEG 16
#define D 128
#define MT 32          // nodes per block
#define XPS 136        // sXp row stride in bf16 elems (272B: 2-way alias, free)

#define XB_BYTES (100000L * 128 * 2)          // 25,600,000
#define WT_BYTES (128L * 128 * 2)             // 32,768
#define WS_NEEDED (XB_BYTES + WT_BYTES)

typedef __attribute__((ext_vector_type(8))) short bf16x8;   // 16 B
typedef __attribute__((ext_vector_type(4))) float f32x4;

__device__ __forceinline__ unsigned short f2bf(float x) {
  union { float f; unsigned u; } v; v.f = x;
  unsigned r = v.u + 0x7FFFu + ((v.u >> 16) & 1u);
  return (unsigned short)(r >> 16);
}
__device__ __forceinline__ float bf2f(short s) {
  union { unsigned u; float f; } t;
  t.u = ((unsigned)(unsigned short)s) << 16;
  return t.f;
}

// ---- prep: W[k][n] fp32 -> Wt[n][k] bf16 (B-frag: 8 consecutive k contiguous)
__global__ __launch_bounds__(256) void prep_wt(const float* __restrict__ W,
                                               unsigned short* __restrict__ Wt) {
  int t = blockIdx.x * 256 + threadIdx.x;
  int n = t >> 7, k = t & 127;
  Wt[n * D + k] = f2bf(W[k * D + n]);
}

// ---- prep: X fp32 -> bf16, coalesced float4 -> ushort4
__global__ __launch_bounds__(256) void prep_x(const float* __restrict__ X,
                                              unsigned short* __restrict__ Xb) {
  long t = (long)blockIdx.x * 256 + threadIdx.x;   // 0 .. 3,199,999
  float4 v = ((const float4*)X)[t];
  ushort4 o;
  o.x = f2bf(v.x); o.y = f2bf(v.y); o.z = f2bf(v.z); o.w = f2bf(v.w);
  ((ushort4*)Xb)[t] = o;
}

// ---- main: bf16 gather + aggregate + MFMA ----
__global__ __launch_bounds__(256) void gin_fused_bf16(
    const unsigned short* __restrict__ Xb, const int* __restrict__ colidx,
    const unsigned short* __restrict__ Wt, float* __restrict__ out) {
  __shared__ __align__(16) unsigned short sXp[MT * XPS];
  __shared__ int sIdx[MT * DEG];

  const int tid  = threadIdx.x;
  const int wave = tid >> 6;
  const int lane = tid & 63;
  const long base_node = (long)blockIdx.x * MT;

  ((int2*)sIdx)[tid] = ((const int2*)(colidx + base_node * DEG))[tid];
  __syncthreads();

  // aggregation: quarter-wave (16 lanes) per node; lane covers 8 cols (16 B).
  // One wave-load = 4 random 256B rows = 1 KB, fully consumed.
  const int q = lane >> 4;   // 0..3: which node of the group of 4
  const int l = lane & 15;   // 16B chunk within the 256B row
  #pragma unroll
  for (int p = 0; p < 2; ++p) {
    int local = wave * 8 + p * 4 + q;
    float acc[8] = {0.f, 0.f, 0.f, 0.f, 0.f, 0.f, 0.f, 0.f};
    #pragma unroll
    for (int j = 0; j < DEG; ++j) {          // 16 independent 16B gathers
      int c = sIdx[local * DEG + j];
      bf16x8 v = *(const bf16x8*)(Xb + (long)c * D + l * 8);
      #pragma unroll
      for (int e = 0; e < 8; ++e) acc[e] += bf2f(v[e]);
    }
    bf16x8 o;
    #pragma unroll
    for (int e = 0; e < 8; ++e) o[e] = (short)f2bf(acc[e]);
    *(bf16x8*)(&sXp[local * XPS + l * 8]) = o;   // ds_write_b128
  }
  __syncthreads();

  // MFMA 16x16x32 bf16: wave w -> n-tiles {2w,2w+1} x m-tiles {0,1}
  const int fr   = lane & 15;
  const int quad = lane >> 4;
  f32x4 acc[2][2] = {{{0.f,0.f,0.f,0.f},{0.f,0.f,0.f,0.f}},
                     {{0.f,0.f,0.f,0.f},{0.f,0.f,0.f,0.f}}};
  #pragma unroll
  for (int ks = 0; ks < 4; ++ks) {
    int k0 = ks * 32 + quad * 8;
    bf16x8 a0 = *(const bf16x8*)(&sXp[fr        * XPS + k0]);
    bf16x8 a1 = *(const bf16x8*)(&sXp[(16 + fr) * XPS + k0]);
    #pragma unroll
    for (int nt = 0; nt < 2; ++nt) {
      int n = (wave * 2 + nt) * 16 + fr;
      bf16x8 bfrag = *(const bf16x8*)(&Wt[n * D + k0]);
      acc[0][nt] = __builtin_amdgcn_mfma_f32_16x16x32_bf16(a0, bfrag, acc[0][nt], 0, 0, 0);
      acc[1][nt] = __builtin_amdgcn_mfma_f32_16x16x32_bf16(a1, bfrag, acc[1][nt], 0, 0, 0);
    }
  }

  #pragma unroll
  for (int mt = 0; mt < 2; ++mt)
    #pragma unroll
    for (int nt = 0; nt < 2; ++nt) {
      int col = (wave * 2 + nt) * 16 + fr;
      long rowbase = base_node + mt * 16 + quad * 4;
      #pragma unroll
      for (int r = 0; r < 4; ++r)
        out[(rowbase + r) * D + col] = acc[mt][nt][r];
    }
}

// ---- fallback (R1 kernel): fp32 gather, used only if ws too small ----
__global__ __launch_bounds__(256) void gin_fused_f32(
    const float* __restrict__ X, const int* __restrict__ colidx,
    const unsigned short* __restrict__ Wt, float* __restrict__ out) {
  __shared__ __align__(16) unsigned short sXp[MT * XPS];
  __shared__ int sIdx[MT * DEG];
  const int tid  = threadIdx.x;
  const int wave = tid >> 6;
  const int lane = tid & 63;
  const long base_node = (long)blockIdx.x * MT;
  ((int2*)sIdx)[tid] = ((const int2*)(colidx + base_node * DEG))[tid];
  __syncthreads();
  const int half = lane >> 5, l32 = lane & 31;
  const float4* X4 = (const float4*)X;
  #pragma unroll
  for (int p = 0; p < 4; ++p) {
    int local = wave * 8 + p * 2 + half;
    float4 acc = make_float4(0.f, 0.f, 0.f, 0.f);
    #pragma unroll
    for (int j = 0; j < DEG; ++j) {
      int c = sIdx[local * DEG + j];
      float4 v = X4[(long)c * (D / 4) + l32];
      acc.x += v.x; acc.y += v.y; acc.z += v.z; acc.w += v.w;
    }
    ushort4 b;
    b.x = f2bf(acc.x); b.y = f2bf(acc.y); b.z = f2bf(acc.z); b.w = f2bf(acc.w);
    *(ushort4*)(&sXp[local * XPS + l32 * 4]) = b;
  }
  __syncthreads();
  const int fr = lane & 15, quad = lane >> 4;
  f32x4 acc[2][2] = {{{0.f,0.f,0.f,0.f},{0.f,0.f,0.f,0.f}},
                     {{0.f,0.f,0.f,0.f},{0.f,0.f,0.f,0.f}}};
  #pragma unroll
  for (int ks = 0; ks < 4; ++ks) {
    int k0 = ks * 32 + quad * 8;
    bf16x8 a0 = *(const bf16x8*)(&sXp[fr        * XPS + k0]);
    bf16x8 a1 = *(const bf16x8*)(&sXp[(16 + fr) * XPS + k0]);
    #pragma unroll
    for (int nt = 0; nt < 2; ++nt) {
      int n = (wave * 2 + nt) * 16 + fr;
      bf16x8 bfrag = *(const bf16x8*)(&Wt[n * D + k0]);
      acc[0][nt] = __builtin_amdgcn_mfma_f32_16x16x32_bf16(a0, bfrag, acc[0][nt], 0, 0, 0);
      acc[1][nt] = __builtin_amdgcn_mfma_f32_16x16x32_bf16(a1, bfrag, acc[1][nt], 0, 0, 0);
    }
  }
  #pragma unroll
  for (int mt = 0; mt < 2; ++mt)
    #pragma unroll
    for (int nt = 0; nt < 2; ++nt) {
      int col = (wave * 2 + nt) * 16 + fr;
      long rowbase = base_node + mt * 16 + quad * 4;
      #pragma unroll
      for (int r = 0; r < 4; ++r)
        out[(rowbase + r) * D + col] = acc[mt][nt][r];
    }
}

extern "C" void kernel_launch(void* const* d_in, const int* in_sizes, int n_in,
                              void* d_out, int out_size, void* d_ws, size_t ws_size,
                              hipStream_t stream) {
  const float* X      = (const float*)d_in[0];
  const float* W      = (const float*)d_in[1];
  const int*   colidx = (const int*)d_in[3];
  float* out = (float*)d_out;

  if (ws_size >= (size_t)WS_NEEDED) {
    unsigned short* Xb = (unsigned short*)d_ws;                  // 25.6 MB bf16 X
    unsigned short* Wt = (unsigned short*)((char*)d_ws + XB_BYTES);
    hipLaunchKernelGGL(prep_wt, dim3(64), dim3(256), 0, stream, W, Wt);
    hipLaunchKernelGGL(prep_x, dim3(12500), dim3(256), 0, stream, X, Xb);
    hipLaunchKernelGGL(gin_fused_bf16, dim3(NNODES / MT), dim3(256), 0, stream,
                       Xb, colidx, Wt, out);
  } else {
    unsigned short* Wt = (unsigned short*)d_ws;                  // 32 KB
    hipLaunchKernelGGL(prep_wt, dim3(64), dim3(256), 0, stream, W, Wt);
    hipLaunchKernelGGL(gin_fused_f32, dim3(NNODES / MT), dim3(256), 0, stream,
                       X, colidx, Wt, out);
  }
}

// Round 3
// 210.924 us; speedup vs baseline: 1.1909x; 1.0049x over previous
//
#include <hip/hip_runtime.h>

// GINConv fused: out[r] = (sum_{j<16} X[col[16r+j]]) @ W
// N=100000, DEG=16, D=128. Latency/MLP-bound on L2/L3 gathers.
// R3: register-batched gather — all 16 neighbor loads issued back-to-back
// (bf16x8 v[16] = 64 VGPRs) before unpacking; __launch_bounds__(256,4)
// raises VGPR budget to 128 so the compiler can't starve the load batch.

#define NNODES 100000
#define DEG 16
#define D 128
#define MT 32          // nodes per block
#define XPS 136        // sXp row stride in bf16 elems (272B: 2-way alias, free)

#define XB_BYTES (100000L * 128 * 2)          // 25,600,000
#define WT_BYTES (128L * 128 * 2)             // 32,768
#define WS_NEEDED (XB_BYTES + WT_BYTES)

typedef __attribute__((ext_vector_type(8))) short bf16x8;   // 16 B
typedef __attribute__((ext_vector_type(4))) float f32x4;

__device__ __forceinline__ unsigned short f2bf(float x) {
  union { float f; unsigned u; } v; v.f = x;
  unsigned r = v.u + 0x7FFFu + ((v.u >> 16) & 1u);
  return (unsigned short)(r >> 16);
}
__device__ __forceinline__ float bf2f(short s) {
  union { unsigned u; float f; } t;
  t.u = ((unsigned)(unsigned short)s) << 16;
  return t.f;
}

// ---- prep: W[k][n] fp32 -> Wt[n][k] bf16 (B-frag: 8 consecutive k contiguous)
__global__ __launch_bounds__(256) void prep_wt(const float* __restrict__ W,
                                               unsigned short* __restrict__ Wt) {
  int t = blockIdx.x * 256 + threadIdx.x;
  int n = t >> 7, k = t & 127;
  Wt[n * D + k] = f2bf(W[k * D + n]);
}

// ---- prep: X fp32 -> bf16, coalesced float4 -> ushort4
__global__ __launch_bounds__(256) void prep_x(const float* __restrict__ X,
                                              unsigned short* __restrict__ Xb) {
  long t = (long)blockIdx.x * 256 + threadIdx.x;   // 0 .. 3,199,999
  float4 v = ((const float4*)X)[t];
  ushort4 o;
  o.x = f2bf(v.x); o.y = f2bf(v.y); o.z = f2bf(v.z); o.w = f2bf(v.w);
  ((ushort4*)Xb)[t] = o;
}

// ---- main: bf16 register-batched gather + aggregate + MFMA ----
__global__ __launch_bounds__(256, 4) void gin_fused_bf16(
    const unsigned short* __restrict__ Xb, const int* __restrict__ colidx,
    const unsigned short* __restrict__ Wt, float* __restrict__ out) {
  __shared__ __align__(16) unsigned short sXp[MT * XPS];
  __shared__ __align__(16) int sIdx[MT * DEG];

  const int tid  = threadIdx.x;
  const int wave = tid >> 6;
  const int lane = tid & 63;
  const long base_node = (long)blockIdx.x * MT;

  ((int2*)sIdx)[tid] = ((const int2*)(colidx + base_node * DEG))[tid];
  __syncthreads();

  // aggregation: quarter-wave (16 lanes) per node; lane covers 8 cols (16 B).
  const int q = lane >> 4;   // node within the group of 4
  const int l = lane & 15;   // 16B chunk within the 256B row
  #pragma unroll
  for (int p = 0; p < 2; ++p) {
    int local = wave * 8 + p * 4 + q;
    // 16 indices via 4 broadcast ds_read_b128 (quarter-wave same address)
    int4 i4[4];
    #pragma unroll
    for (int t = 0; t < 4; ++t) i4[t] = ((const int4*)(sIdx + local * DEG))[t];
    int idx[16] = {i4[0].x, i4[0].y, i4[0].z, i4[0].w,
                   i4[1].x, i4[1].y, i4[1].z, i4[1].w,
                   i4[2].x, i4[2].y, i4[2].z, i4[2].w,
                   i4[3].x, i4[3].y, i4[3].z, i4[3].w};
    // all 16 gathers in flight before any unpack
    bf16x8 v[DEG];
    #pragma unroll
    for (int j = 0; j < DEG; ++j)
      v[j] = *(const bf16x8*)(Xb + (long)idx[j] * D + l * 8);
    float acc[8] = {0.f, 0.f, 0.f, 0.f, 0.f, 0.f, 0.f, 0.f};
    #pragma unroll
    for (int j = 0; j < DEG; ++j)
      #pragma unroll
      for (int e = 0; e < 8; ++e) acc[e] += bf2f(v[j][e]);
    bf16x8 o;
    #pragma unroll
    for (int e = 0; e < 8; ++e) o[e] = (short)f2bf(acc[e]);
    *(bf16x8*)(&sXp[local * XPS + l * 8]) = o;   // ds_write_b128
  }
  __syncthreads();

  // MFMA 16x16x32 bf16: wave w -> n-tiles {2w,2w+1} x m-tiles {0,1}
  const int fr   = lane & 15;
  const int quad = lane >> 4;
  f32x4 acc[2][2] = {{{0.f,0.f,0.f,0.f},{0.f,0.f,0.f,0.f}},
                     {{0.f,0.f,0.f,0.f},{0.f,0.f,0.f,0.f}}};
  #pragma unroll
  for (int ks = 0; ks < 4; ++ks) {
    int k0 = ks * 32 + quad * 8;
    bf16x8 a0 = *(const bf16x8*)(&sXp[fr        * XPS + k0]);
    bf16x8 a1 = *(const bf16x8*)(&sXp[(16 + fr) * XPS + k0]);
    #pragma unroll
    for (int nt = 0; nt < 2; ++nt) {
      int n = (wave * 2 + nt) * 16 + fr;
      bf16x8 bfrag = *(const bf16x8*)(&Wt[n * D + k0]);
      acc[0][nt] = __builtin_amdgcn_mfma_f32_16x16x32_bf16(a0, bfrag, acc[0][nt], 0, 0, 0);
      acc[1][nt] = __builtin_amdgcn_mfma_f32_16x16x32_bf16(a1, bfrag, acc[1][nt], 0, 0, 0);
    }
  }

  #pragma unroll
  for (int mt = 0; mt < 2; ++mt)
    #pragma unroll
    for (int nt = 0; nt < 2; ++nt) {
      int col = (wave * 2 + nt) * 16 + fr;
      long rowbase = base_node + mt * 16 + quad * 4;
      #pragma unroll
      for (int r = 0; r < 4; ++r)
        out[(rowbase + r) * D + col] = acc[mt][nt][r];
    }
}

// ---- fallback: fp32 gather, used only if ws too small ----
__global__ __launch_bounds__(256) void gin_fused_f32(
    const float* __restrict__ X, const int* __restrict__ colidx,
    const unsigned short* __restrict__ Wt, float* __restrict__ out) {
  __shared__ __align__(16) unsigned short sXp[MT * XPS];
  __shared__ int sIdx[MT * DEG];
  const int tid  = threadIdx.x;
  const int wave = tid >> 6;
  const int lane = tid & 63;
  const long base_node = (long)blockIdx.x * MT;
  ((int2*)sIdx)[tid] = ((const int2*)(colidx + base_node * DEG))[tid];
  __syncthreads();
  const int half = lane >> 5, l32 = lane & 31;
  const float4* X4 = (const float4*)X;
  #pragma unroll
  for (int p = 0; p < 4; ++p) {
    int local = wave * 8 + p * 2 + half;
    float4 acc = make_float4(0.f, 0.f, 0.f, 0.f);
    #pragma unroll
    for (int j = 0; j < DEG; ++j) {
      int c = sIdx[local * DEG + j];
      float4 v = X4[(long)c * (D / 4) + l32];
      acc.x += v.x; acc.y += v.y; acc.z += v.z; acc.w += v.w;
    }
    ushort4 b;
    b.x = f2bf(acc.x); b.y = f2bf(acc.y); b.z = f2bf(acc.z); b.w = f2bf(acc.w);
    *(ushort4*)(&sXp[local * XPS + l32 * 4]) = b;
  }
  __syncthreads();
  const int fr = lane & 15, quad = lane >> 4;
  f32x4 acc[2][2] = {{{0.f,0.f,0.f,0.f},{0.f,0.f,0.f,0.f}},
                     {{0.f,0.f,0.f,0.f},{0.f,0.f,0.f,0.f}}};
  #pragma unroll
  for (int ks = 0; ks < 4; ++ks) {
    int k0 = ks * 32 + quad * 8;
    bf16x8 a0 = *(const bf16x8*)(&sXp[fr        * XPS + k0]);
    bf16x8 a1 = *(const bf16x8*)(&sXp[(16 + fr) * XPS + k0]);
    #pragma unroll
    for (int nt = 0; nt < 2; ++nt) {
      int n = (wave * 2 + nt) * 16 + fr;
      bf16x8 bfrag = *(const bf16x8*)(&Wt[n * D + k0]);
      acc[0][nt] = __builtin_amdgcn_mfma_f32_16x16x32_bf16(a0, bfrag, acc[0][nt], 0, 0, 0);
      acc[1][nt] = __builtin_amdgcn_mfma_f32_16x16x32_bf16(a1, bfrag, acc[1][nt], 0, 0, 0);
    }
  }
  #pragma unroll
  for (int mt = 0; mt < 2; ++mt)
    #pragma unroll
    for (int nt = 0; nt < 2; ++nt) {
      int col = (wave * 2 + nt) * 16 + fr;
      long rowbase = base_node + mt * 16 + quad * 4;
      #pragma unroll
      for (int r = 0; r < 4; ++r)
        out[(rowbase + r) * D + col] = acc[mt][nt][r];
    }
}

extern "C" void kernel_launch(void* const* d_in, const int* in_sizes, int n_in,
                              void* d_out, int out_size, void* d_ws, size_t ws_size,
                              hipStream_t stream) {
  const float* X      = (const float*)d_in[0];
  const float* W      = (const float*)d_in[1];
  const int*   colidx = (const int*)d_in[3];
  float* out = (float*)d_out;

  if (ws_size >= (size_t)WS_NEEDED) {
    unsigned short* Xb = (unsigned short*)d_ws;                  // 25.6 MB bf16 X
    unsigned short* Wt = (unsigned short*)((char*)d_ws + XB_BYTES);
    hipLaunchKernelGGL(prep_wt, dim3(64), dim3(256), 0, stream, W, Wt);
    hipLaunchKernelGGL(prep_x, dim3(12500), dim3(256), 0, stream, X, Xb);
    hipLaunchKernelGGL(gin_fused_bf16, dim3(NNODES / MT), dim3(256), 0, stream,
                       Xb, colidx, Wt, out);
  } else {
    unsigned short* Wt = (unsigned short*)d_ws;                  // 32 KB
    hipLaunchKernelGGL(prep_wt, dim3(64), dim3(256), 0, stream, W, Wt);
    hipLaunchKernelGGL(gin_fused_f32, dim3(NNODES / MT), dim3(256), 0, stream,
                       X, colidx, Wt, out);
  }
}

// Round 4
// 208.801 us; speedup vs baseline: 1.2030x; 1.0102x over previous
//
#include <hip/hip_runtime.h>

// GINConv fused: out[r] = (sum_{j<16} X[col[16r+j]]) @ W
// N=100000, DEG=16, D=128. Latency/MLP-bound on L2/L3 gathers.
// R4: sched_barrier(0) pins the 16-load gather batch — compiler must keep
// all 16 global_load_dwordx4 in flight (v[16] = 64 VGPRs) before unpacking.

#define NNODES 100000
#define DEG 16
#define D 128
#define MT 32          // nodes per block
#define XPS 136        // sXp row stride in bf16 elems (272B: 2-way alias, free)

#define XB_BYTES (100000L * 128 * 2)          // 25,600,000
#define WT_BYTES (128L * 128 * 2)             // 32,768
#define WS_NEEDED (XB_BYTES + WT_BYTES)

typedef __attribute__((ext_vector_type(8))) short bf16x8;   // 16 B
typedef __attribute__((ext_vector_type(4))) float f32x4;

__device__ __forceinline__ unsigned short f2bf(float x) {
  union { float f; unsigned u; } v; v.f = x;
  unsigned r = v.u + 0x7FFFu + ((v.u >> 16) & 1u);
  return (unsigned short)(r >> 16);
}
__device__ __forceinline__ float bf2f(short s) {
  union { unsigned u; float f; } t;
  t.u = ((unsigned)(unsigned short)s) << 16;
  return t.f;
}

// ---- prep: W[k][n] fp32 -> Wt[n][k] bf16 (B-frag: 8 consecutive k contiguous)
__global__ __launch_bounds__(256) void prep_wt(const float* __restrict__ W,
                                               unsigned short* __restrict__ Wt) {
  int t = blockIdx.x * 256 + threadIdx.x;
  int n = t >> 7, k = t & 127;
  Wt[n * D + k] = f2bf(W[k * D + n]);
}

// ---- prep: X fp32 -> bf16, coalesced float4 -> ushort4
__global__ __launch_bounds__(256) void prep_x(const float* __restrict__ X,
                                              unsigned short* __restrict__ Xb) {
  long t = (long)blockIdx.x * 256 + threadIdx.x;   // 0 .. 3,199,999
  float4 v = ((const float4*)X)[t];
  ushort4 o;
  o.x = f2bf(v.x); o.y = f2bf(v.y); o.z = f2bf(v.z); o.w = f2bf(v.w);
  ((ushort4*)Xb)[t] = o;
}

// ---- main: bf16 register-batched gather (pinned) + aggregate + MFMA ----
__global__ __launch_bounds__(256, 4) void gin_fused_bf16(
    const unsigned short* __restrict__ Xb, const int* __restrict__ colidx,
    const unsigned short* __restrict__ Wt, float* __restrict__ out) {
  __shared__ __align__(16) unsigned short sXp[MT * XPS];
  __shared__ __align__(16) int sIdx[MT * DEG];

  const int tid  = threadIdx.x;
  const int wave = tid >> 6;
  const int lane = tid & 63;
  const long base_node = (long)blockIdx.x * MT;

  ((int2*)sIdx)[tid] = ((const int2*)(colidx + base_node * DEG))[tid];
  __syncthreads();

  // aggregation: quarter-wave (16 lanes) per node; lane covers 8 cols (16 B).
  const int q = lane >> 4;   // node within the group of 4
  const int l = lane & 15;   // 16B chunk within the 256B row
  #pragma unroll
  for (int p = 0; p < 2; ++p) {
    int local = wave * 8 + p * 4 + q;
    // 16 indices via 4 broadcast ds_read_b128 (quarter-wave same address)
    int4 i4[4];
    #pragma unroll
    for (int t = 0; t < 4; ++t) i4[t] = ((const int4*)(sIdx + local * DEG))[t];
    int idx[16] = {i4[0].x, i4[0].y, i4[0].z, i4[0].w,
                   i4[1].x, i4[1].y, i4[1].z, i4[1].w,
                   i4[2].x, i4[2].y, i4[2].z, i4[2].w,
                   i4[3].x, i4[3].y, i4[3].z, i4[3].w};
    // --- pinned load batch: all 16 gathers issued before ANY unpack ---
    bf16x8 v[DEG];
    #pragma unroll
    for (int j = 0; j < DEG; ++j)
      v[j] = *(const bf16x8*)(Xb + (long)idx[j] * D + l * 8);
    __builtin_amdgcn_sched_barrier(0);   // nothing crosses: batch stays intact
    float acc[8] = {0.f, 0.f, 0.f, 0.f, 0.f, 0.f, 0.f, 0.f};
    #pragma unroll
    for (int j = 0; j < DEG; ++j)
      #pragma unroll
      for (int e = 0; e < 8; ++e) acc[e] += bf2f(v[j][e]);
    bf16x8 o;
    #pragma unroll
    for (int e = 0; e < 8; ++e) o[e] = (short)f2bf(acc[e]);
    *(bf16x8*)(&sXp[local * XPS + l * 8]) = o;   // ds_write_b128
  }
  __syncthreads();

  // MFMA 16x16x32 bf16: wave w -> n-tiles {2w,2w+1} x m-tiles {0,1}
  const int fr   = lane & 15;
  const int quad = lane >> 4;
  f32x4 acc[2][2] = {{{0.f,0.f,0.f,0.f},{0.f,0.f,0.f,0.f}},
                     {{0.f,0.f,0.f,0.f},{0.f,0.f,0.f,0.f}}};
  #pragma unroll
  for (int ks = 0; ks < 4; ++ks) {
    int k0 = ks * 32 + quad * 8;
    bf16x8 a0 = *(const bf16x8*)(&sXp[fr        * XPS + k0]);
    bf16x8 a1 = *(const bf16x8*)(&sXp[(16 + fr) * XPS + k0]);
    #pragma unroll
    for (int nt = 0; nt < 2; ++nt) {
      int n = (wave * 2 + nt) * 16 + fr;
      bf16x8 bfrag = *(const bf16x8*)(&Wt[n * D + k0]);
      acc[0][nt] = __builtin_amdgcn_mfma_f32_16x16x32_bf16(a0, bfrag, acc[0][nt], 0, 0, 0);
      acc[1][nt] = __builtin_amdgcn_mfma_f32_16x16x32_bf16(a1, bfrag, acc[1][nt], 0, 0, 0);
    }
  }

  #pragma unroll
  for (int mt = 0; mt < 2; ++mt)
    #pragma unroll
    for (int nt = 0; nt < 2; ++nt) {
      int col = (wave * 2 + nt) * 16 + fr;
      long rowbase = base_node + mt * 16 + quad * 4;
      #pragma unroll
      for (int r = 0; r < 4; ++r)
        out[(rowbase + r) * D + col] = acc[mt][nt][r];
    }
}

// ---- fallback: fp32 gather, used only if ws too small ----
__global__ __launch_bounds__(256) void gin_fused_f32(
    const float* __restrict__ X, const int* __restrict__ colidx,
    const unsigned short* __restrict__ Wt, float* __restrict__ out) {
  __shared__ __align__(16) unsigned short sXp[MT * XPS];
  __shared__ int sIdx[MT * DEG];
  const int tid  = threadIdx.x;
  const int wave = tid >> 6;
  const int lane = tid & 63;
  const long base_node = (long)blockIdx.x * MT;
  ((int2*)sIdx)[tid] = ((const int2*)(colidx + base_node * DEG))[tid];
  __syncthreads();
  const int half = lane >> 5, l32 = lane & 31;
  const float4* X4 = (const float4*)X;
  #pragma unroll
  for (int p = 0; p < 4; ++p) {
    int local = wave * 8 + p * 2 + half;
    float4 acc = make_float4(0.f, 0.f, 0.f, 0.f);
    #pragma unroll
    for (int j = 0; j < DEG; ++j) {
      int c = sIdx[local * DEG + j];
      float4 v = X4[(long)c * (D / 4) + l32];
      acc.x += v.x; acc.y += v.y; acc.z += v.z; acc.w += v.w;
    }
    ushort4 b;
    b.x = f2bf(acc.x); b.y = f2bf(acc.y); b.z = f2bf(acc.z); b.w = f2bf(acc.w);
    *(ushort4*)(&sXp[local * XPS + l32 * 4]) = b;
  }
  __syncthreads();
  const int fr = lane & 15, quad = lane >> 4;
  f32x4 acc[2][2] = {{{0.f,0.f,0.f,0.f},{0.f,0.f,0.f,0.f}},
                     {{0.f,0.f,0.f,0.f},{0.f,0.f,0.f,0.f}}};
  #pragma unroll
  for (int ks = 0; ks < 4; ++ks) {
    int k0 = ks * 32 + quad * 8;
    bf16x8 a0 = *(const bf16x8*)(&sXp[fr        * XPS + k0]);
    bf16x8 a1 = *(const bf16x8*)(&sXp[(16 + fr) * XPS + k0]);
    #pragma unroll
    for (int nt = 0; nt < 2; ++nt) {
      int n = (wave * 2 + nt) * 16 + fr;
      bf16x8 bfrag = *(const bf16x8*)(&Wt[n * D + k0]);
      acc[0][nt] = __builtin_amdgcn_mfma_f32_16x16x32_bf16(a0, bfrag, acc[0][nt], 0, 0, 0);
      acc[1][nt] = __builtin_amdgcn_mfma_f32_16x16x32_bf16(a1, bfrag, acc[1][nt], 0, 0, 0);
    }
  }
  #pragma unroll
  for (int mt = 0; mt < 2; ++mt)
    #pragma unroll
    for (int nt = 0; nt < 2; ++nt) {
      int col = (wave * 2 + nt) * 16 + fr;
      long rowbase = base_node + mt * 16 + quad * 4;
      #pragma unroll
      for (int r = 0; r < 4; ++r)
        out[(rowbase + r) * D + col] = acc[mt][nt][r];
    }
}

extern "C" void kernel_launch(void* const* d_in, const int* in_sizes, int n_in,
                              void* d_out, int out_size, void* d_ws, size_t ws_size,
                              hipStream_t stream) {
  const float* X      = (const float*)d_in[0];
  const float* W      = (const float*)d_in[1];
  const int*   colidx = (const int*)d_in[3];
  float* out = (float*)d_out;

  if (ws_size >= (size_t)WS_NEEDED) {
    unsigned short* Xb = (unsigned short*)d_ws;                  // 25.6 MB bf16 X
    unsigned short* Wt = (unsigned short*)((char*)d_ws + XB_BYTES);
    hipLaunchKernelGGL(prep_wt, dim3(64), dim3(256), 0, stream, W, Wt);
    hipLaunchKernelGGL(prep_x, dim3(12500), dim3(256), 0, stream, X, Xb);
    hipLaunchKernelGGL(gin_fused_bf16, dim3(NNODES / MT), dim3(256), 0, stream,
                       Xb, colidx, Wt, out);
  } else {
    unsigned short* Wt = (unsigned short*)d_ws;                  // 32 KB
    hipLaunchKernelGGL(prep_wt, dim3(64), dim3(256), 0, stream, W, Wt);
    hipLaunchKernelGGL(gin_fused_f32, dim3(NNODES / MT), dim3(256), 0, stream,
                       X, colidx, Wt, out);
  }
}